// Round 1
// 696.918 us; speedup vs baseline: 1.0023x; 1.0023x over previous
//
#include <hip/hip_runtime.h>
#include <hip/hip_bf16.h>
#include <cstdint>
#include <cstddef>

// Problem dims (fixed)
#define B_  32
#define S_  2048
#define E_  1024
#define A_  1024
#define D_  1024
#define M_TOT (B_ * S_)     // 65536 rows of flattened [B*S, E]

typedef __attribute__((ext_vector_type(8))) __bf16 bf16x8;
typedef __attribute__((ext_vector_type(4))) float  f32x4;

__device__ __forceinline__ float fast_tanh(float x) {
    float cx = fminf(fmaxf(x, -15.f), 15.f);
    float e2 = __expf(2.f * cx);
    return 1.f - 2.f / (e2 + 1.f);
}

__device__ __forceinline__ bf16x8 pack8(float4 f0, float4 f1) {
    bf16x8 r;
    r[0] = (__bf16)f0.x; r[1] = (__bf16)f0.y; r[2] = (__bf16)f0.z; r[3] = (__bf16)f0.w;
    r[4] = (__bf16)f1.x; r[5] = (__bf16)f1.y; r[6] = (__bf16)f1.z; r[7] = (__bf16)f1.w;
    return r;
}

// async global->LDS, 16 B per lane; lds dest = wave-uniform base + lane*16.
typedef __attribute__((address_space(3))) uint32_t lds_u32_t;
typedef __attribute__((address_space(1))) const uint32_t gbl_u32_t;
__device__ __forceinline__ void async_ld16(const void* g, void* l) {
    __builtin_amdgcn_global_load_lds((gbl_u32_t*)g,
                                     (lds_u32_t*)(uint32_t)(uintptr_t)l,
                                     16, 0, 0);
}

// ---------------- k0: enc fp32 -> bf16 (one pass; removes 8x-redundant per-block
//                  conversion from the e-GEMM inner loop) ----------------
__global__ __launch_bounds__(256) void k_cvt(const float* __restrict__ enc,
                                             __bf16* __restrict__ encB) {
    size_t base = (size_t)blockIdx.x * 8192 + (size_t)threadIdx.x * 8;
    #pragma unroll
    for (int it = 0; it < 4; ++it) {
        size_t idx = base + (size_t)it * 2048;
        float4 f0 = *(const float4*)(enc + idx);
        float4 f1 = *(const float4*)(enc + idx + 4);
        *(bf16x8*)(encB + idx) = pack8(f0, f1);
    }
}

// ---------------- k1: U_a transpose via LDS tile (coalesced both sides) ----------------
__global__ __launch_bounds__(256) void k_trans_U(const float* __restrict__ Ua,
                                                 __bf16* __restrict__ Ut) {
    __shared__ float tile[64][65];          // +1 pad: conflict-free column reads
    int bid = blockIdx.x;                   // 256 = 16 k-tiles x 16 n-tiles
    int k0 = (bid >> 4) * 64, n0 = (bid & 15) * 64;
    int t = threadIdx.x;
    int r = t >> 6, c = t & 63;             // r: 0..3 (wave id), c: lane
    #pragma unroll
    for (int i = 0; i < 16; ++i)
        tile[i * 4 + r][c] = Ua[(size_t)(k0 + i * 4 + r) * 1024 + n0 + c];
    __syncthreads();
    #pragma unroll
    for (int i = 0; i < 16; ++i)
        Ut[(size_t)(n0 + i * 4 + r) * 1024 + k0 + c] = (__bf16)tile[c][i * 4 + r];
}

// ---------------- k2: w partials, K split 8 ways ----------------
__global__ __launch_bounds__(256) void k_w_part(const float* __restrict__ dec,
                                                const float* __restrict__ Wa,
                                                float* __restrict__ w_part) {
    int bid = blockIdx.x;            // 1024 = kc(8) x b(32) x ac(4)
    int ac = bid & 3, b = (bid >> 2) & 31, kc = bid >> 7;
    int a = ac * 256 + threadIdx.x;
    int k0 = kc * 128;
    float acc = 0.f;
    #pragma unroll 8
    for (int k = 0; k < 128; ++k)
        acc += dec[b * 1024 + k0 + k] * Wa[(size_t)(k0 + k) * 1024 + a];
    w_part[kc * 32768 + b * 1024 + a] = acc;
}

// ---------------- k3: fused e-GEMM ----------------
// 128x128 tile, BK=32, double-buffered LDS, 1 barrier / 32-K step (m97 structure).
//
// LDS layout is XOR-swizzled to kill the 4-bank-group ds_read_b128 conflicts
// (1.68e7 conflict cycles/dispatch measured on the linear layout):
//   phys granule (16B unit in a 64-B row) = logical_granule ^ ((row>>1)&3)
// Since global_load_lds writes linearly (base + lane*16, rule m104/m173), the
// swizzle is realized by pre-swizzling the *global source column* per lane and
// XOR-ing the fragment *read* address; LDS writes stay linear (conflict-free).
//
// ASYNC_A=1: A comes pre-converted (encB bf16) via global_load_lds — no VALU
//            convert in the loop.  ASYNC_A=0: fallback (ws too small), fp32
//            loads + pack8 + linear ds_write_b128 (also conflict-free).
//
// MFMA layouts (verified m89/m91): A/B frag: m|n = lane&15, k = (lane>>4)*8+j
//                                   C/D:     col = lane&15, row = (lane>>4)*4 + reg
template<bool ASYNC_A>
__global__ __launch_bounds__(256) void k_gemm_e(
        const float* __restrict__ enc, const __bf16* __restrict__ encB,
        const __bf16* __restrict__ Ut,
        const float* __restrict__ w_part, const float* __restrict__ v,
        float* __restrict__ e_part) {
    __shared__ __bf16 lX[2][128 * 32];
    __shared__ __bf16 lU[2][128 * 32];
    __shared__ float  e_lds[2][128];

    const int t = threadIdx.x;
    // XCD swizzle: keep all 8 n-tiles of an m-tile on one XCD (L2 reuse).
    const int bid = blockIdx.x;            // 0..4095
    const int xcd = bid & 7;
    const int j_  = bid >> 3;              // 0..511
    const int m_tile = xcd * 64 + (j_ >> 3);
    const int n_tile = j_ & 7;
    const int m0 = m_tile * 128;
    const int n0 = n_tile * 128;
    const int wave = t >> 6;
    const int lane = t & 63;
    const int q = lane >> 4;
    const int c = lane & 15;
    const int wm = (wave >> 1) * 64;
    const int wn = (wave & 1) * 64;

    f32x4 acc[4][4];
    #pragma unroll
    for (int i = 0; i < 4; ++i)
        #pragma unroll
        for (int j = 0; j < 4; ++j)
            #pragma unroll
            for (int r = 0; r < 4; ++r) acc[i][j][r] = 0.f;

    // staging mapping: wave covers rows [xrow, xrow+32)
    // lane -> (row = xrow + lrow (+16), phys granule p = lane&3)
    // source column is pre-swizzled: logical granule = p ^ sw(row)
    const int lrow = lane >> 2;            // 0..15
    const int p    = lane & 3;             // phys 16B granule within 64-B row
    const int sw   = (lrow >> 1) & 3;      // == (row>>1)&3 for both row chunks
    const int lcolS = ((p ^ sw)) * 8;      // element col of the data this lane stages

    const int xrow = wave * 32;

    const float*  gxa = enc  + (size_t)(m0 + xrow + lrow) * 1024 + lcolS;
    const __bf16* gxb = encB + (size_t)(m0 + xrow + lrow) * 1024 + lcolS;
    const __bf16* gub = Ut   + (size_t)(n0 + xrow + lrow) * 1024 + lcolS;

    float4 f0, f1, f2, f3;
    auto loadA = [&](int kk) {
        const float* pp = gxa + kk;
        f0 = *(const float4*)pp;
        f1 = *(const float4*)(pp + 4);
        f2 = *(const float4*)(pp + 16 * 1024);
        f3 = *(const float4*)(pp + 16 * 1024 + 4);
    };
    auto writeA = [&](int bsel) {   // linear phys write (conflict-free)
        *(bf16x8*)(&lX[bsel][(xrow + lrow) * 32 + p * 8])      = pack8(f0, f1);
        *(bf16x8*)(&lX[bsel][(xrow + 16 + lrow) * 32 + p * 8]) = pack8(f2, f3);
    };
    auto stageA = [&](int kk, int bsel) {
        async_ld16(gxb + kk,             &lX[bsel][xrow * 32]);
        async_ld16(gxb + kk + 16 * 1024, &lX[bsel][(xrow + 16) * 32]);
    };
    auto stageB = [&](int kk, int bsel) {
        async_ld16(gub + kk,             &lU[bsel][xrow * 32]);
        async_ld16(gub + kk + 16 * 1024, &lU[bsel][(xrow + 16) * 32]);
    };

    // fragment reads: row = W + i*16 + c  ->  (row>>1)&3 == (c>>1)&3, lane-constant
    const int fcol = (q ^ ((c >> 1) & 3)) * 8;   // swizzled phys granule
    auto compute = [&](int bsel) {
        bf16x8 af[4], bfr[4];
        #pragma unroll
        for (int i = 0; i < 4; ++i)
            af[i] = *(const bf16x8*)(&lX[bsel][(wm + i * 16 + c) * 32 + fcol]);
        #pragma unroll
        for (int j = 0; j < 4; ++j)
            bfr[j] = *(const bf16x8*)(&lU[bsel][(wn + j * 16 + c) * 32 + fcol]);
        #pragma unroll
        for (int i = 0; i < 4; ++i)
            #pragma unroll
            for (int j = 0; j < 4; ++j)
                acc[i][j] = __builtin_amdgcn_mfma_f32_16x16x32_bf16(af[i], bfr[j], acc[i][j], 0, 0, 0);
    };

    if constexpr (ASYNC_A) {
        // both operands async: pure m97 structure (2 barriers / 64-K)
        stageA(0, 0); stageB(0, 0);
        __syncthreads();
        for (int kk = 0; kk < 1024; kk += 64) {
            if (kk + 32 < 1024) { stageA(kk + 32, 1); stageB(kk + 32, 1); }
            compute(0);
            __syncthreads();
            if (kk + 64 < 1024) { stageA(kk + 64, 0); stageB(kk + 64, 0); }
            compute(1);
            __syncthreads();
        }
    } else {
        // fallback: on-the-fly fp32->bf16 A
        loadA(0);
        stageB(0, 0);
        writeA(0);
        __syncthreads();
        for (int kk = 0; kk < 1024; kk += 64) {
            if (kk + 32 < 1024) { loadA(kk + 32); stageB(kk + 32, 1); }
            compute(0);
            if (kk + 32 < 1024) writeA(1);
            __syncthreads();
            if (kk + 64 < 1024) { loadA(kk + 64); stageB(kk + 64, 0); }
            compute(1);
            if (kk + 64 < 1024) writeA(0);
            __syncthreads();
        }
    }

    // epilogue: e_row_partial = sum_cols v[col]*tanh(w[b,col] + u)
    const int b_idx = m0 >> 11;
    float wv[4], vv[4];
    #pragma unroll
    for (int j = 0; j < 4; ++j) {
        int col = n0 + wn + j * 16 + c;
        float s = 0.f;
        #pragma unroll
        for (int pp = 0; pp < 8; ++pp) s += w_part[pp * 32768 + b_idx * 1024 + col];
        wv[j] = s;
        vv[j] = v[col];
    }
    #pragma unroll
    for (int i = 0; i < 4; ++i) {
        float s0 = 0.f, s1 = 0.f, s2 = 0.f, s3 = 0.f;
        #pragma unroll
        for (int j = 0; j < 4; ++j) {
            s0 += fast_tanh(wv[j] + acc[i][j][0]) * vv[j];
            s1 += fast_tanh(wv[j] + acc[i][j][1]) * vv[j];
            s2 += fast_tanh(wv[j] + acc[i][j][2]) * vv[j];
            s3 += fast_tanh(wv[j] + acc[i][j][3]) * vv[j];
        }
        #pragma unroll
        for (int off = 1; off < 16; off <<= 1) {
            s0 += __shfl_xor(s0, off, 16);
            s1 += __shfl_xor(s1, off, 16);
            s2 += __shfl_xor(s2, off, 16);
            s3 += __shfl_xor(s3, off, 16);
        }
        if (c == 0) {
            int row = wm + i * 16 + q * 4;
            e_lds[wave & 1][row + 0] = s0;
            e_lds[wave & 1][row + 1] = s1;
            e_lds[wave & 1][row + 2] = s2;
            e_lds[wave & 1][row + 3] = s3;
        }
    }
    __syncthreads();
    if (t < 128)
        e_part[(size_t)n_tile * M_TOT + m0 + t] = e_lds[0][t] + e_lds[1][t];
}

// ---------------- k4: softmax over S per batch ----------------
__global__ __launch_bounds__(256) void k_softmax(const float* __restrict__ ep,
                                                 float* __restrict__ al) {
    int b = blockIdx.x, t = threadIdx.x;
    float ev[8];
    #pragma unroll
    for (int i = 0; i < 8; ++i) {
        int s = i * 256 + t;
        float x = 0.f;
        #pragma unroll
        for (int p = 0; p < 8; ++p) x += ep[p * M_TOT + b * 2048 + s];
        ev[i] = x;
    }
    float mx = ev[0];
    #pragma unroll
    for (int i = 1; i < 8; ++i) mx = fmaxf(mx, ev[i]);
    #pragma unroll
    for (int off = 1; off < 64; off <<= 1) mx = fmaxf(mx, __shfl_xor(mx, off, 64));
    __shared__ float redm[4];
    if ((t & 63) == 0) redm[t >> 6] = mx;
    __syncthreads();
    mx = fmaxf(fmaxf(redm[0], redm[1]), fmaxf(redm[2], redm[3]));

    float ex[8], sm = 0.f;
    #pragma unroll
    for (int i = 0; i < 8; ++i) { ex[i] = __expf(ev[i] - mx); sm += ex[i]; }
    #pragma unroll
    for (int off = 1; off < 64; off <<= 1) sm += __shfl_xor(sm, off, 64);
    __shared__ float reds[4];
    if ((t & 63) == 0) reds[t >> 6] = sm;
    __syncthreads();
    sm = reds[0] + reds[1] + reds[2] + reds[3];
    float inv = 1.f / sm;
    #pragma unroll
    for (int i = 0; i < 8; ++i) al[b * 2048 + i * 256 + t] = ex[i] * inv;
}

// ---------------- k5: context partials (fp32 enc) ----------------
// ctx_part[sc][b][e] = sum over 64-row chunk sc of al[b,s]*enc[b,s,e]
__global__ __launch_bounds__(256) void k_ctx(const float* __restrict__ enc,
                                             const float* __restrict__ al,
                                             float* __restrict__ ctx_part) {
    int b  = blockIdx.x >> 5;
    int sc = blockIdx.x & 31;
    int t  = threadIdx.x;
    int e4 = t * 4;
    float ax = 0.f, ay = 0.f, az = 0.f, aw = 0.f;
    int sbase = sc * 64;
    for (int i = 0; i < 64; i += 4) {
        #pragma unroll
        for (int u = 0; u < 4; ++u) {
            int s = sbase + i + u;
            float a = al[b * 2048 + s];
            float4 x = *(const float4*)(enc + (size_t)(b * 2048 + s) * 1024 + e4);
            ax += a * x.x; ay += a * x.y; az += a * x.z; aw += a * x.w;
        }
    }
    float4 r; r.x = ax; r.y = ay; r.z = az; r.w = aw;
    *(float4*)(ctx_part + ((size_t)sc * 32 + b) * 1024 + e4) = r;
}

// ---------------- k6: final — ctx reduce + context out + FFN GEMV + tanh ----------------
// grid 512 = b(32) x dc(16); block handles 64 output dims, full K=2048.
__global__ __launch_bounds__(256) void k_final(const float* __restrict__ dec,
                                               const float* __restrict__ ffn,
                                               const float* __restrict__ ctx_part,
                                               float* __restrict__ out) {
    int b  = blockIdx.x >> 4;
    int dc = blockIdx.x & 15;
    int t  = threadIdx.x;
    __shared__ float cat[2048];
    __shared__ float red[4][64];

    // build cat = [dec(1024) | ctx(1024)] in LDS; ctx = sum of 32 partial planes
    #pragma unroll
    for (int r = 0; r < 4; ++r) {
        int e = r * 256 + t;
        cat[e] = dec[b * 1024 + e];
        float s = 0.f;
        #pragma unroll
        for (int p = 0; p < 32; ++p) s += ctx_part[((size_t)p * 32 + b) * 1024 + e];
        cat[1024 + e] = s;
        if (dc == 0) out[32768 + b * 1024 + e] = s;   // context output
    }
    __syncthreads();

    int dl = t & 63, ic = t >> 6;                     // d-lane, i-chunk
    int d  = dc * 64 + dl;
    float acc = 0.f;
    int i0 = ic * 512;
    for (int i = 0; i < 512; i += 4) {
        float4 cv = *(const float4*)(cat + i0 + i);   // broadcast ds_read_b128
        const float* fr = ffn + (size_t)(i0 + i) * 1024 + d;
        acc += cv.x * fr[0];
        acc += cv.y * fr[1024];
        acc += cv.z * fr[2048];
        acc += cv.w * fr[3072];
    }
    red[ic][dl] = acc;
    __syncthreads();
    if (t < 64) {
        float s = red[0][t] + red[1][t] + red[2][t] + red[3][t];
        out[b * 1024 + dc * 64 + t] = fast_tanh(s);
    }
}

// ---------------- launch ----------------
extern "C" void kernel_launch(void* const* d_in, const int* in_sizes, int n_in,
                              void* d_out, int out_size, void* d_ws, size_t ws_size,
                              hipStream_t stream) {
    const float* enc = (const float*)d_in[0];
    const float* dec = (const float*)d_in[1];
    const float* Ua  = (const float*)d_in[2];
    const float* Wa  = (const float*)d_in[3];
    const float* vt  = (const float*)d_in[4];
    const float* ffn = (const float*)d_in[5];
    float* out = (float*)d_out;

    char* ws = (char*)d_ws;
    size_t off = 0;
    __bf16* Ut       = (__bf16*)(ws + off); off += (size_t)A_ * E_ * 2;            // 2 MiB
    float*  e_part   = (float*)(ws + off);  off += (size_t)8 * M_TOT * 4;          // 2 MiB
    float*  al       = (float*)(ws + off);  off += (size_t)M_TOT * 4;              // 256 KiB
    float*  w_part   = (float*)(ws + off);  off += (size_t)8 * B_ * 1024 * 4;      // 1 MiB
    float*  ctx_part = (float*)(ws + off);  off += (size_t)32 * B_ * 1024 * 4;     // 4 MiB
    __bf16* encB     = (__bf16*)(ws + off); off += (size_t)M_TOT * E_ * 2;         // 128 MiB
    const bool use_async = ws_size >= off;

    k_trans_U<<<256, 256, 0, stream>>>(Ua, Ut);
    k_w_part<<<1024, 256, 0, stream>>>(dec, Wa, w_part);
    if (use_async) {
        k_cvt<<<8192, 256, 0, stream>>>(enc, encB);
        k_gemm_e<true><<<4096, 256, 0, stream>>>(enc, encB, Ut, w_part, vt, e_part);
    } else {
        k_gemm_e<false><<<4096, 256, 0, stream>>>(enc, encB, Ut, w_part, vt, e_part);
    }
    k_softmax<<<B_, 256, 0, stream>>>(e_part, al);
    k_ctx<<<B_ * 32, 256, 0, stream>>>(enc, al, ctx_part);
    k_final<<<B_ * 16, 256, 0, stream>>>(dec, ffn, ctx_part, out);
}

// Round 2
// 631.829 us; speedup vs baseline: 1.1056x; 1.1030x over previous
//
#include <hip/hip_runtime.h>
#include <hip/hip_bf16.h>
#include <cstdint>
#include <cstddef>

// Problem dims (fixed)
#define B_  32
#define S_  2048
#define E_  1024
#define A_  1024
#define D_  1024
#define M_TOT (B_ * S_)     // 65536 rows of flattened [B*S, E]

typedef __attribute__((ext_vector_type(8))) __bf16 bf16x8;
typedef __attribute__((ext_vector_type(4))) float  f32x4;

__device__ __forceinline__ float fast_tanh(float x) {
    float cx = fminf(fmaxf(x, -15.f), 15.f);
    float e2 = __expf(2.f * cx);
    return 1.f - 2.f / (e2 + 1.f);
}

__device__ __forceinline__ bf16x8 pack8(float4 f0, float4 f1) {
    bf16x8 r;
    r[0] = (__bf16)f0.x; r[1] = (__bf16)f0.y; r[2] = (__bf16)f0.z; r[3] = (__bf16)f0.w;
    r[4] = (__bf16)f1.x; r[5] = (__bf16)f1.y; r[6] = (__bf16)f1.z; r[7] = (__bf16)f1.w;
    return r;
}

// async global->LDS, 16 B per lane; lds dest = wave-uniform base + lane*16.
typedef __attribute__((address_space(3))) uint32_t lds_u32_t;
typedef __attribute__((address_space(1))) const uint32_t gbl_u32_t;
__device__ __forceinline__ void async_ld16(const void* g, void* l) {
    __builtin_amdgcn_global_load_lds((gbl_u32_t*)g,
                                     (lds_u32_t*)(uint32_t)(uintptr_t)l,
                                     16, 0, 0);
}

// ---------------- k0: enc fp32 -> bf16 ----------------
__global__ __launch_bounds__(256) void k_cvt(const float* __restrict__ enc,
                                             __bf16* __restrict__ encB) {
    size_t base = (size_t)blockIdx.x * 8192 + (size_t)threadIdx.x * 8;
    #pragma unroll
    for (int it = 0; it < 4; ++it) {
        size_t idx = base + (size_t)it * 2048;
        float4 f0 = *(const float4*)(enc + idx);
        float4 f1 = *(const float4*)(enc + idx + 4);
        *(bf16x8*)(encB + idx) = pack8(f0, f1);
    }
}

// ---------------- k1: U_a transpose via LDS tile ----------------
__global__ __launch_bounds__(256) void k_trans_U(const float* __restrict__ Ua,
                                                 __bf16* __restrict__ Ut) {
    __shared__ float tile[64][65];
    int bid = blockIdx.x;
    int k0 = (bid >> 4) * 64, n0 = (bid & 15) * 64;
    int t = threadIdx.x;
    int r = t >> 6, c = t & 63;
    #pragma unroll
    for (int i = 0; i < 16; ++i)
        tile[i * 4 + r][c] = Ua[(size_t)(k0 + i * 4 + r) * 1024 + n0 + c];
    __syncthreads();
    #pragma unroll
    for (int i = 0; i < 16; ++i)
        Ut[(size_t)(n0 + i * 4 + r) * 1024 + k0 + c] = (__bf16)tile[c][i * 4 + r];
}

// ---------------- k2: w partials, K split 8 ways ----------------
__global__ __launch_bounds__(256) void k_w_part(const float* __restrict__ dec,
                                                const float* __restrict__ Wa,
                                                float* __restrict__ w_part) {
    int bid = blockIdx.x;            // 1024 = kc(8) x b(32) x ac(4)
    int ac = bid & 3, b = (bid >> 2) & 31, kc = bid >> 7;
    int a = ac * 256 + threadIdx.x;
    int k0 = kc * 128;
    float acc = 0.f;
    #pragma unroll 8
    for (int k = 0; k < 128; ++k)
        acc += dec[b * 1024 + k0 + k] * Wa[(size_t)(k0 + k) * 1024 + a];
    w_part[kc * 32768 + b * 1024 + a] = acc;
}

// ---------------- k3: 8-phase 256x256 e-GEMM (T2+T3+T4+T5) ----------------
// BM=BN=256, BK=64, 8 waves (2M x 4N), per-wave 128x64 output.
// LDS 128 KiB: [buf][A/B][256 rows x 64 k] bf16, double-buffered per K-tile.
// Swizzle: phys 16B-granule = logical ^ (row&7); staged via pre-swizzled
// global source col ((lane&7)^(lane>>3)), read with granule^(c&7). Both
// sides wave-balanced (8 lanes per granule) -> conflict-free.
// Schedule per K-tile kt (buf=kt&1), 4 phases, raw s_barrier (NO vmcnt drain):
//   P0: ds_read A(mh0) 8x + B(nh0) 4x | stage H(kt+1,A1,B1)->buf^1 | bar | mma(0,0)
//   P1: ds_read B(nh1) 4x                                          | bar | mma(0,1)
//   P2: ds_read A(mh1) 8x                                          | bar | mma(1,1)
//   P3: stage H(kt+2,A0,B0)->buf (regions fully read by P1/P2)     | bar | mma(1,0)
//       then counted vmcnt(4) (H(kt+1) complete, H(kt+2) stays in flight) + bar
// Prologue: stage tile0 (4 halves) + tile1 (A0,B0), vmcnt(4).
#define PBAR  __builtin_amdgcn_s_barrier()
#define LGKM0 asm volatile("s_waitcnt lgkmcnt(0)" ::: "memory")

#define DS_A(mh) do { \
    _Pragma("unroll") for (int mf = 0; mf < 4; ++mf) \
        _Pragma("unroll") for (int k2 = 0; k2 < 2; ++k2) \
            a[mf][k2] = *(const bf16x8*)&L[buf][0][(wm + (mh)*64 + mf*16 + c)*64 + (((k2*4 + q) ^ (c & 7)))*8]; \
} while (0)

#define DS_B(nh, bb) do { \
    _Pragma("unroll") for (int nf = 0; nf < 2; ++nf) \
        _Pragma("unroll") for (int k2 = 0; k2 < 2; ++k2) \
            bb[nf][k2] = *(const bf16x8*)&L[buf][1][(wn + (nh)*32 + nf*16 + c)*64 + (((k2*4 + q) ^ (c & 7)))*8]; \
} while (0)

#define MMA_Q(mh, nh, bb) do { \
    __builtin_amdgcn_s_setprio(1); \
    _Pragma("unroll") for (int mf = 0; mf < 4; ++mf) \
        _Pragma("unroll") for (int nf = 0; nf < 2; ++nf) \
            _Pragma("unroll") for (int k2 = 0; k2 < 2; ++k2) \
                acc[(mh)*4 + mf][(nh)*2 + nf] = __builtin_amdgcn_mfma_f32_16x16x32_bf16( \
                    a[mf][k2], bb[nf][k2], acc[(mh)*4 + mf][(nh)*2 + nf], 0, 0, 0); \
    __builtin_amdgcn_s_setprio(0); \
} while (0)

__global__ __launch_bounds__(512, 2) void k_gemm8(
        const __bf16* __restrict__ encB, const __bf16* __restrict__ Ut,
        const float* __restrict__ w_part, const float* __restrict__ v,
        float* __restrict__ e_part) {
    __shared__ __bf16 L[2][2][16384];   // 128 KiB

    const int t = threadIdx.x;
    const int wid = t >> 6, lane = t & 63;
    const int q = lane >> 4, c = lane & 15;
    const int wm = (wid >> 2) * 128;     // 2 M-wave groups
    const int wn = (wid & 3) * 64;       // 4 N-wave groups

    // XCD-chunked: 1024 = xcd(8) x m(32) x n(4); n-siblings adjacent on one XCD.
    const int p = blockIdx.x;
    const int xcd = p & 7, j = p >> 3;
    const int m_tile = xcd * 32 + (j >> 2);
    const int n_tile = j & 3;
    const int m0 = m_tile * 256, n0 = n_tile * 256;

    // staging: granule index g = l*512 + t; row = g>>3, phys granule = g&7,
    // source logical granule = (g&7) ^ (row&7) = (lane&7)^(lane>>3) per lane.
    const int scol = ((lane & 7) ^ (lane >> 3)) * 8;
    const __bf16* gA = encB + (size_t)(m0 + (t >> 3)) * 1024 + scol;
    const __bf16* gB = Ut   + (size_t)(n0 + (t >> 3)) * 1024 + scol;
    const int ldsoff0 = wid * 512;       // elems; + lane*16B implicit in builtin

    auto stage = [&](int kind, int h, int kt2) {
        const __bf16* src = (kind ? gB : gA) + (size_t)h * 128 * 1024 + (size_t)kt2 * 64;
        __bf16* dst = &L[kt2 & 1][kind][h * 8192 + ldsoff0];
        async_ld16(src,             dst);
        async_ld16(src + 64 * 1024, dst + 4096);   // +512 granules = +64 rows
    };

    f32x4 acc[8][4];
    #pragma unroll
    for (int i = 0; i < 8; ++i)
        #pragma unroll
        for (int jj = 0; jj < 4; ++jj)
            #pragma unroll
            for (int r = 0; r < 4; ++r) acc[i][jj][r] = 0.f;

    bf16x8 a[4][2], b0[2][2], b1[2][2];

    // prologue: tile0 all 4 halves + tile1 A0,B0 -> 12 loads; vmcnt(4) => tile0 done
    stage(0, 0, 0); stage(1, 0, 0); stage(0, 1, 0); stage(1, 1, 0);
    stage(0, 0, 1); stage(1, 0, 1);
    asm volatile("s_waitcnt vmcnt(4)" ::: "memory");
    PBAR;
    __builtin_amdgcn_sched_barrier(0);

    #pragma unroll 2
    for (int kt = 0; kt < 16; ++kt) {
        const int buf = kt & 1;
        // ---- P0 ----
        DS_A(0);
        DS_B(0, b0);
        if (kt < 15) { stage(0, 1, kt + 1); stage(1, 1, kt + 1); }
        PBAR; LGKM0;
        MMA_Q(0, 0, b0);
        PBAR;
        // ---- P1 ----
        DS_B(1, b1);
        PBAR; LGKM0;
        MMA_Q(0, 1, b1);
        PBAR;
        // ---- P2 ----
        DS_A(1);
        PBAR; LGKM0;
        MMA_Q(1, 1, b1);
        PBAR;
        // ---- P3 ----
        if (kt < 14) { stage(0, 0, kt + 2); stage(1, 0, kt + 2); }
        PBAR;
        MMA_Q(1, 0, b0);
        if (kt < 15) {
            if (kt < 14) asm volatile("s_waitcnt vmcnt(4)" ::: "memory");
            else         asm volatile("s_waitcnt vmcnt(0)" ::: "memory");
            PBAR;
            __builtin_amdgcn_sched_barrier(0);
        }
    }

    // ---- epilogue: e_row_partial = sum_{n in tile} v[n]*tanh(w[b,n] + u[m,n]) ----
    __syncthreads();                      // all waves done with L; reuse as e_red
    float* e_red = (float*)&L[0][0][0];   // [4][256]

    const int b_idx = m0 >> 11;           // 256-row tile sits in one batch
    float wv[4], vv[4];
    #pragma unroll
    for (int nf = 0; nf < 4; ++nf) {
        int col = n0 + wn + nf * 16 + c;
        float s = 0.f;
        #pragma unroll
        for (int pp = 0; pp < 8; ++pp) s += w_part[pp * 32768 + b_idx * 1024 + col];
        wv[nf] = s;
        vv[nf] = v[col];
    }
    #pragma unroll
    for (int mf = 0; mf < 8; ++mf) {
        float s0 = 0.f, s1 = 0.f, s2 = 0.f, s3 = 0.f;
        #pragma unroll
        for (int nf = 0; nf < 4; ++nf) {
            s0 += fast_tanh(wv[nf] + acc[mf][nf][0]) * vv[nf];
            s1 += fast_tanh(wv[nf] + acc[mf][nf][1]) * vv[nf];
            s2 += fast_tanh(wv[nf] + acc[mf][nf][2]) * vv[nf];
            s3 += fast_tanh(wv[nf] + acc[mf][nf][3]) * vv[nf];
        }
        #pragma unroll
        for (int off = 1; off < 16; off <<= 1) {
            s0 += __shfl_xor(s0, off, 16);
            s1 += __shfl_xor(s1, off, 16);
            s2 += __shfl_xor(s2, off, 16);
            s3 += __shfl_xor(s3, off, 16);
        }
        if (c == 0) {
            int row = wm + mf * 16 + q * 4;
            e_red[(wid & 3) * 256 + row + 0] = s0;
            e_red[(wid & 3) * 256 + row + 1] = s1;
            e_red[(wid & 3) * 256 + row + 2] = s2;
            e_red[(wid & 3) * 256 + row + 3] = s3;
        }
    }
    __syncthreads();
    if (t < 256)
        e_part[(size_t)n_tile * M_TOT + m0 + t] =
            e_red[t] + e_red[256 + t] + e_red[512 + t] + e_red[768 + t];
}

// ---------------- fallback e-GEMM (ws too small): round-1 128-tile kernel ----------------
__global__ __launch_bounds__(256) void k_gemm_fb(
        const float* __restrict__ enc, const __bf16* __restrict__ Ut,
        const float* __restrict__ w_part, const float* __restrict__ v,
        float* __restrict__ e_part) {
    __shared__ __bf16 lX[2][128 * 32];
    __shared__ __bf16 lU[2][128 * 32];
    __shared__ float  e_lds[2][128];

    const int t = threadIdx.x;
    const int bid = blockIdx.x;
    const int xcd = bid & 7;
    const int j_  = bid >> 3;
    const int m_tile = xcd * 64 + (j_ >> 3);
    const int n_tile = j_ & 7;
    const int m0 = m_tile * 128;
    const int n0 = n_tile * 128;
    const int wave = t >> 6;
    const int lane = t & 63;
    const int q = lane >> 4;
    const int c = lane & 15;
    const int wm = (wave >> 1) * 64;
    const int wn = (wave & 1) * 64;

    f32x4 acc[4][4];
    #pragma unroll
    for (int i = 0; i < 4; ++i)
        #pragma unroll
        for (int j = 0; j < 4; ++j)
            #pragma unroll
            for (int r = 0; r < 4; ++r) acc[i][j][r] = 0.f;

    const int lrow = lane >> 2;
    const int p    = lane & 3;
    const int sw   = (lrow >> 1) & 3;
    const int lcolS = ((p ^ sw)) * 8;
    const int xrow = wave * 32;

    const float*  gxa = enc + (size_t)(m0 + xrow + lrow) * 1024 + lcolS;
    const __bf16* gub = Ut  + (size_t)(n0 + xrow + lrow) * 1024 + lcolS;

    float4 f0, f1, f2, f3;
    auto loadA = [&](int kk) {
        const float* pp = gxa + kk;
        f0 = *(const float4*)pp;
        f1 = *(const float4*)(pp + 4);
        f2 = *(const float4*)(pp + 16 * 1024);
        f3 = *(const float4*)(pp + 16 * 1024 + 4);
    };
    auto writeA = [&](int bsel) {
        *(bf16x8*)(&lX[bsel][(xrow + lrow) * 32 + p * 8])      = pack8(f0, f1);
        *(bf16x8*)(&lX[bsel][(xrow + 16 + lrow) * 32 + p * 8]) = pack8(f2, f3);
    };
    auto stageB = [&](int kk, int bsel) {
        async_ld16(gub + kk,             &lU[bsel][xrow * 32]);
        async_ld16(gub + kk + 16 * 1024, &lU[bsel][(xrow + 16) * 32]);
    };
    const int fcol = (q ^ ((c >> 1) & 3)) * 8;
    auto compute = [&](int bsel) {
        bf16x8 af[4], bfr[4];
        #pragma unroll
        for (int i = 0; i < 4; ++i)
            af[i] = *(const bf16x8*)(&lX[bsel][(wm + i * 16 + c) * 32 + fcol]);
        #pragma unroll
        for (int j = 0; j < 4; ++j)
            bfr[j] = *(const bf16x8*)(&lU[bsel][(wn + j * 16 + c) * 32 + fcol]);
        #pragma unroll
        for (int i = 0; i < 4; ++i)
            #pragma unroll
            for (int j = 0; j < 4; ++j)
                acc[i][j] = __builtin_amdgcn_mfma_f32_16x16x32_bf16(af[i], bfr[j], acc[i][j], 0, 0, 0);
    };

    loadA(0);
    stageB(0, 0);
    writeA(0);
    __syncthreads();
    for (int kk = 0; kk < 1024; kk += 64) {
        if (kk + 32 < 1024) { loadA(kk + 32); stageB(kk + 32, 1); }
        compute(0);
        if (kk + 32 < 1024) writeA(1);
        __syncthreads();
        if (kk + 64 < 1024) { loadA(kk + 64); stageB(kk + 64, 0); }
        compute(1);
        if (kk + 64 < 1024) writeA(0);
        __syncthreads();
    }

    const int b_idx = m0 >> 11;
    float wv[4], vv[4];
    #pragma unroll
    for (int j = 0; j < 4; ++j) {
        int col = n0 + wn + j * 16 + c;
        float s = 0.f;
        #pragma unroll
        for (int pp = 0; pp < 8; ++pp) s += w_part[pp * 32768 + b_idx * 1024 + col];
        wv[j] = s;
        vv[j] = v[col];
    }
    #pragma unroll
    for (int i = 0; i < 4; ++i) {
        float s0 = 0.f, s1 = 0.f, s2 = 0.f, s3 = 0.f;
        #pragma unroll
        for (int j = 0; j < 4; ++j) {
            s0 += fast_tanh(wv[j] + acc[i][j][0]) * vv[j];
            s1 += fast_tanh(wv[j] + acc[i][j][1]) * vv[j];
            s2 += fast_tanh(wv[j] + acc[i][j][2]) * vv[j];
            s3 += fast_tanh(wv[j] + acc[i][j][3]) * vv[j];
        }
        #pragma unroll
        for (int off = 1; off < 16; off <<= 1) {
            s0 += __shfl_xor(s0, off, 16);
            s1 += __shfl_xor(s1, off, 16);
            s2 += __shfl_xor(s2, off, 16);
            s3 += __shfl_xor(s3, off, 16);
        }
        if (c == 0) {
            int row = wm + i * 16 + q * 4;
            e_lds[wave & 1][row + 0] = s0;
            e_lds[wave & 1][row + 1] = s1;
            e_lds[wave & 1][row + 2] = s2;
            e_lds[wave & 1][row + 3] = s3;
        }
    }
    __syncthreads();
    if (t < 128)
        e_part[(size_t)n_tile * M_TOT + m0 + t] = e_lds[0][t] + e_lds[1][t];
}

// ---------------- k4: softmax over S per batch (P partial planes) ----------------
template<int NP>
__global__ __launch_bounds__(256) void k_softmax(const float* __restrict__ ep,
                                                 float* __restrict__ al) {
    int b = blockIdx.x, t = threadIdx.x;
    float ev[8];
    #pragma unroll
    for (int i = 0; i < 8; ++i) {
        int s = i * 256 + t;
        float x = 0.f;
        #pragma unroll
        for (int p = 0; p < NP; ++p) x += ep[p * M_TOT + b * 2048 + s];
        ev[i] = x;
    }
    float mx = ev[0];
    #pragma unroll
    for (int i = 1; i < 8; ++i) mx = fmaxf(mx, ev[i]);
    #pragma unroll
    for (int off = 1; off < 64; off <<= 1) mx = fmaxf(mx, __shfl_xor(mx, off, 64));
    __shared__ float redm[4];
    if ((t & 63) == 0) redm[t >> 6] = mx;
    __syncthreads();
    mx = fmaxf(fmaxf(redm[0], redm[1]), fmaxf(redm[2], redm[3]));

    float ex[8], sm = 0.f;
    #pragma unroll
    for (int i = 0; i < 8; ++i) { ex[i] = __expf(ev[i] - mx); sm += ex[i]; }
    #pragma unroll
    for (int off = 1; off < 64; off <<= 1) sm += __shfl_xor(sm, off, 64);
    __shared__ float reds[4];
    if ((t & 63) == 0) reds[t >> 6] = sm;
    __syncthreads();
    sm = reds[0] + reds[1] + reds[2] + reds[3];
    float inv = 1.f / sm;
    #pragma unroll
    for (int i = 0; i < 8; ++i) al[b * 2048 + i * 256 + t] = ex[i] * inv;
}

// ---------------- k5: context partials (fp32 enc) ----------------
__global__ __launch_bounds__(256) void k_ctx(const float* __restrict__ enc,
                                             const float* __restrict__ al,
                                             float* __restrict__ ctx_part) {
    int b  = blockIdx.x >> 5;
    int sc = blockIdx.x & 31;
    int t  = threadIdx.x;
    int e4 = t * 4;
    float ax = 0.f, ay = 0.f, az = 0.f, aw = 0.f;
    int sbase = sc * 64;
    for (int i = 0; i < 64; i += 4) {
        #pragma unroll
        for (int u = 0; u < 4; ++u) {
            int s = sbase + i + u;
            float a = al[b * 2048 + s];
            float4 x = *(const float4*)(enc + (size_t)(b * 2048 + s) * 1024 + e4);
            ax += a * x.x; ay += a * x.y; az += a * x.z; aw += a * x.w;
        }
    }
    float4 r; r.x = ax; r.y = ay; r.z = az; r.w = aw;
    *(float4*)(ctx_part + ((size_t)sc * 32 + b) * 1024 + e4) = r;
}

// ---------------- k6: final — ctx reduce + context out + FFN GEMV + tanh ----------------
__global__ __launch_bounds__(256) void k_final(const float* __restrict__ dec,
                                               const float* __restrict__ ffn,
                                               const float* __restrict__ ctx_part,
                                               float* __restrict__ out) {
    int b  = blockIdx.x >> 4;
    int dc = blockIdx.x & 15;
    int t  = threadIdx.x;
    __shared__ float cat[2048];
    __shared__ float red[4][64];

    #pragma unroll
    for (int r = 0; r < 4; ++r) {
        int e = r * 256 + t;
        cat[e] = dec[b * 1024 + e];
        float s = 0.f;
        #pragma unroll
        for (int p = 0; p < 32; ++p) s += ctx_part[((size_t)p * 32 + b) * 1024 + e];
        cat[1024 + e] = s;
        if (dc == 0) out[32768 + b * 1024 + e] = s;   // context output
    }
    __syncthreads();

    int dl = t & 63, ic = t >> 6;
    int d  = dc * 64 + dl;
    float acc = 0.f;
    int i0 = ic * 512;
    for (int i = 0; i < 512; i += 4) {
        float4 cv = *(const float4*)(cat + i0 + i);
        const float* fr = ffn + (size_t)(i0 + i) * 1024 + d;
        acc += cv.x * fr[0];
        acc += cv.y * fr[1024];
        acc += cv.z * fr[2048];
        acc += cv.w * fr[3072];
    }
    red[ic][dl] = acc;
    __syncthreads();
    if (t < 64) {
        float s = red[0][t] + red[1][t] + red[2][t] + red[3][t];
        out[b * 1024 + dc * 64 + t] = fast_tanh(s);
    }
}

// ---------------- launch ----------------
extern "C" void kernel_launch(void* const* d_in, const int* in_sizes, int n_in,
                              void* d_out, int out_size, void* d_ws, size_t ws_size,
                              hipStream_t stream) {
    const float* enc = (const float*)d_in[0];
    const float* dec = (const float*)d_in[1];
    const float* Ua  = (const float*)d_in[2];
    const float* Wa  = (const float*)d_in[3];
    const float* vt  = (const float*)d_in[4];
    const float* ffn = (const float*)d_in[5];
    float* out = (float*)d_out;

    char* ws = (char*)d_ws;
    size_t off = 0;
    __bf16* Ut       = (__bf16*)(ws + off); off += (size_t)A_ * E_ * 2;            // 2 MiB
    float*  e_part   = (float*)(ws + off);  off += (size_t)8 * M_TOT * 4;          // 2 MiB (max 8 planes)
    float*  al       = (float*)(ws + off);  off += (size_t)M_TOT * 4;              // 256 KiB
    float*  w_part   = (float*)(ws + off);  off += (size_t)8 * B_ * 1024 * 4;      // 1 MiB
    float*  ctx_part = (float*)(ws + off);  off += (size_t)32 * B_ * 1024 * 4;     // 4 MiB
    __bf16* encB     = (__bf16*)(ws + off); off += (size_t)M_TOT * E_ * 2;         // 128 MiB
    const bool use_async = ws_size >= off;

    k_trans_U<<<256, 256, 0, stream>>>(Ua, Ut);
    k_w_part<<<1024, 256, 0, stream>>>(dec, Wa, w_part);
    if (use_async) {
        k_cvt<<<8192, 256, 0, stream>>>(enc, encB);
        k_gemm8<<<1024, 512, 0, stream>>>(encB, Ut, w_part, vt, e_part);
        k_softmax<4><<<B_, 256, 0, stream>>>(e_part, al);
    } else {
        k_gemm_fb<<<4096, 256, 0, stream>>>(enc, Ut, w_part, vt, e_part);
        k_softmax<8><<<B_, 256, 0, stream>>>(e_part, al);
    }
    k_ctx<<<B_ * 32, 256, 0, stream>>>(enc, al, ctx_part);
    k_final<<<B_ * 16, 256, 0, stream>>>(dec, ffn, ctx_part, out);
}

// Round 3
// 613.060 us; speedup vs baseline: 1.1394x; 1.0306x over previous
//
#include <hip/hip_runtime.h>
#include <hip/hip_bf16.h>
#include <cstdint>
#include <cstddef>

// Problem dims (fixed)
#define B_  32
#define S_  2048
#define E_  1024
#define A_  1024
#define D_  1024
#define M_TOT (B_ * S_)     // 65536 rows of flattened [B*S, E]

typedef __attribute__((ext_vector_type(8))) __bf16 bf16x8;
typedef __attribute__((ext_vector_type(4))) float  f32x4;

__device__ __forceinline__ float fast_tanh(float x) {
    float cx = fminf(fmaxf(x, -15.f), 15.f);
    float e2 = __expf(2.f * cx);
    return 1.f - 2.f / (e2 + 1.f);
}

__device__ __forceinline__ bf16x8 pack8(float4 f0, float4 f1) {
    bf16x8 r;
    r[0] = (__bf16)f0.x; r[1] = (__bf16)f0.y; r[2] = (__bf16)f0.z; r[3] = (__bf16)f0.w;
    r[4] = (__bf16)f1.x; r[5] = (__bf16)f1.y; r[6] = (__bf16)f1.z; r[7] = (__bf16)f1.w;
    return r;
}

// async global->LDS, 16 B per lane; lds dest = wave-uniform base + lane*16.
typedef __attribute__((address_space(3))) uint32_t lds_u32_t;
typedef __attribute__((address_space(1))) const uint32_t gbl_u32_t;
__device__ __forceinline__ void async_ld16(const void* g, void* l) {
    __builtin_amdgcn_global_load_lds((gbl_u32_t*)g,
                                     (lds_u32_t*)(uint32_t)(uintptr_t)l,
                                     16, 0, 0);
}

// ---------------- k_prep: fused {enc fp32->bf16, U_a transpose, w partials} ----------------
// grid = 8192 (cvt) + 256 (transU) + 1024 (w_part); dispatch on blockIdx.
__global__ __launch_bounds__(256) void k_prep(const float* __restrict__ enc,
                                              __bf16* __restrict__ encB,
                                              const float* __restrict__ Ua,
                                              __bf16* __restrict__ Ut,
                                              const float* __restrict__ dec,
                                              const float* __restrict__ Wa,
                                              float* __restrict__ w_part) {
    __shared__ float tile[64][65];
    int bid = blockIdx.x;
    int t = threadIdx.x;
    if (bid < 8192) {
        // ---- cvt ----
        size_t base = (size_t)bid * 8192 + (size_t)t * 8;
        #pragma unroll
        for (int it = 0; it < 4; ++it) {
            size_t idx = base + (size_t)it * 2048;
            float4 f0 = *(const float4*)(enc + idx);
            float4 f1 = *(const float4*)(enc + idx + 4);
            *(bf16x8*)(encB + idx) = pack8(f0, f1);
        }
    } else if (bid < 8448) {
        // ---- transpose U ----
        int b2 = bid - 8192;
        int k0 = (b2 >> 4) * 64, n0 = (b2 & 15) * 64;
        int r = t >> 6, c = t & 63;
        #pragma unroll
        for (int i = 0; i < 16; ++i)
            tile[i * 4 + r][c] = Ua[(size_t)(k0 + i * 4 + r) * 1024 + n0 + c];
        __syncthreads();
        #pragma unroll
        for (int i = 0; i < 16; ++i)
            Ut[(size_t)(n0 + i * 4 + r) * 1024 + k0 + c] = (__bf16)tile[c][i * 4 + r];
    } else {
        // ---- w partials: 1024 = kc(8) x b(32) x ac(4) ----
        int b3 = bid - 8448;
        int ac = b3 & 3, b = (b3 >> 2) & 31, kc = b3 >> 7;
        int a = ac * 256 + t;
        int k0 = kc * 128;
        float acc = 0.f;
        #pragma unroll 8
        for (int k = 0; k < 128; ++k)
            acc += dec[b * 1024 + k0 + k] * Wa[(size_t)(k0 + k) * 1024 + a];
        w_part[kc * 32768 + b * 1024 + a] = acc;
    }
}

// ---------------- k3: 256x256 e-GEMM, 2-barrier/tile counted-vmcnt schedule ----------------
// BM=BN=256, BK=64, 8 waves (2M x 4N). LDS 128 KiB double-buffered.
// A wave-row ownership is INTERLEAVED (wmb + mh*128) so region1's A reads hit
// exactly A-half0 (rows 0-127) and region2's hit A-half1 — this lets A-half1's
// staging stay in flight across region1.
// Per tile kt (buf=kt&1); entry invariant: A0,B0,B1(buf) complete+visible,
// A1(buf) = oldest 2 outstanding vmem ops.
//   R1: ds_read A0(8)+B0(4)+B1(4) | stage A0,B0,B1(kt+1)->buf^1 (6)
//       | MMA Q(0,0),Q(0,1) | vmcnt(6) [A1(kt) done] | s_barrier
//   R2: ds_read A1(8) | stage A1(kt+1) (2)
//       | MMA Q(1,0),Q(1,1) | vmcnt(2) [kt+1 A0B0B1 done] | s_barrier
// Compiler handles all lgkmcnt (C++ ds_reads -> fine-grained counted waits).
#define PBAR  __builtin_amdgcn_s_barrier()
#define SCHED0 __builtin_amdgcn_sched_barrier(0)

#define DS_A(mh) do { \
    _Pragma("unroll") for (int mf = 0; mf < 4; ++mf) \
        _Pragma("unroll") for (int k2 = 0; k2 < 2; ++k2) \
            a[mf][k2] = *(const bf16x8*)&L[buf][0][(wmb + (mh)*128 + mf*16 + c)*64 + (((k2*4 + q) ^ (c & 7)))*8]; \
} while (0)

#define DS_B(nh, bb) do { \
    _Pragma("unroll") for (int nf = 0; nf < 2; ++nf) \
        _Pragma("unroll") for (int k2 = 0; k2 < 2; ++k2) \
            bb[nf][k2] = *(const bf16x8*)&L[buf][1][(wn + (nh)*32 + nf*16 + c)*64 + (((k2*4 + q) ^ (c & 7)))*8]; \
} while (0)

#define MMA_Q(mh, nh, bb) do { \
    __builtin_amdgcn_s_setprio(1); \
    _Pragma("unroll") for (int mf = 0; mf < 4; ++mf) \
        _Pragma("unroll") for (int nf = 0; nf < 2; ++nf) \
            _Pragma("unroll") for (int k2 = 0; k2 < 2; ++k2) \
                acc[(mh)*4 + mf][(nh)*2 + nf] = __builtin_amdgcn_mfma_f32_16x16x32_bf16( \
                    a[mf][k2], bb[nf][k2], acc[(mh)*4 + mf][(nh)*2 + nf], 0, 0, 0); \
    __builtin_amdgcn_s_setprio(0); \
} while (0)

__global__ __launch_bounds__(512, 2) void k_gemm8(
        const __bf16* __restrict__ encB, const __bf16* __restrict__ Ut,
        const float* __restrict__ w_part, const float* __restrict__ v,
        float* __restrict__ e_part) {
    __shared__ __bf16 L[2][2][16384];   // 128 KiB

    const int t = threadIdx.x;
    const int wid = t >> 6, lane = t & 63;
    const int q = lane >> 4, c = lane & 15;
    const int wmb = (wid >> 2) * 64;     // interleaved A-row base: rows wmb+mh*128+..
    const int wn  = (wid & 3) * 64;      // 4 N-wave groups

    // XCD-chunked: 1024 = xcd(8) x m(32) x n(4); n-siblings adjacent on one XCD.
    const int p = blockIdx.x;
    const int xcd = p & 7, j = p >> 3;
    const int m_tile = xcd * 32 + (j >> 2);
    const int n_tile = j & 3;
    const int m0 = m_tile * 256, n0 = n_tile * 256;

    // staging: thread t covers row (t>>3) (+64 for 2nd call), phys granule lane&7;
    // source logical granule = (lane&7) ^ (row&7) = (lane&7)^(lane>>3).
    const int scol = ((lane & 7) ^ (lane >> 3)) * 8;
    const __bf16* gA = encB + (size_t)(m0 + (t >> 3)) * 1024 + scol;
    const __bf16* gB = Ut   + (size_t)(n0 + (t >> 3)) * 1024 + scol;
    const int ldsoff0 = wid * 512;

    auto stage = [&](int kind, int h, int kt2) {
        const __bf16* src = (kind ? gB : gA) + (size_t)h * 128 * 1024 + (size_t)kt2 * 64;
        __bf16* dst = &L[kt2 & 1][kind][h * 8192 + ldsoff0];
        async_ld16(src,             dst);
        async_ld16(src + 64 * 1024, dst + 4096);
    };

    f32x4 acc[8][4];
    #pragma unroll
    for (int i = 0; i < 8; ++i)
        #pragma unroll
        for (int jj = 0; jj < 4; ++jj)
            #pragma unroll
            for (int r = 0; r < 4; ++r) acc[i][jj][r] = 0.f;

    bf16x8 a[4][2], b0[2][2], b1[2][2];

    // prologue: A0,B0,B1 of tile0 (6 loads), then A1 (2 loads); complete first 6.
    stage(0, 0, 0); stage(1, 0, 0); stage(1, 1, 0);
    stage(0, 1, 0);
    asm volatile("s_waitcnt vmcnt(2)" ::: "memory");
    PBAR; SCHED0;

    #pragma unroll 2
    for (int kt = 0; kt < 16; ++kt) {
        const int buf = kt & 1;
        // ---- region 1: A-half0 + all B ----
        DS_A(0);
        DS_B(0, b0);
        DS_B(1, b1);
        if (kt < 15) { stage(0, 0, kt + 1); stage(1, 0, kt + 1); stage(1, 1, kt + 1); }
        MMA_Q(0, 0, b0);
        MMA_Q(0, 1, b1);
        if (kt < 15) asm volatile("s_waitcnt vmcnt(6)" ::: "memory");
        else         asm volatile("s_waitcnt vmcnt(0)" ::: "memory");
        PBAR; SCHED0;
        // ---- region 2: A-half1 ----
        DS_A(1);
        if (kt < 15) stage(0, 1, kt + 1);
        MMA_Q(1, 0, b0);
        MMA_Q(1, 1, b1);
        if (kt < 15) {
            asm volatile("s_waitcnt vmcnt(2)" ::: "memory");
            PBAR; SCHED0;
        }
    }

    // ---- epilogue: e_row_partial = sum_{n in tile} v[n]*tanh(w[b,n] + u[m,n]) ----
    __syncthreads();                      // full drain; reuse L as e_red
    float* e_red = (float*)&L[0][0][0];   // [4][256]

    const int b_idx = m0 >> 11;           // 256-row tile sits in one batch
    float wv[4], vv[4];
    #pragma unroll
    for (int nf = 0; nf < 4; ++nf) {
        int col = n0 + wn + nf * 16 + c;
        float s = 0.f;
        #pragma unroll
        for (int pp = 0; pp < 8; ++pp) s += w_part[pp * 32768 + b_idx * 1024 + col];
        wv[nf] = s;
        vv[nf] = v[col];
    }
    #pragma unroll
    for (int mf8 = 0; mf8 < 8; ++mf8) {
        float s0 = 0.f, s1 = 0.f, s2 = 0.f, s3 = 0.f;
        #pragma unroll
        for (int nf = 0; nf < 4; ++nf) {
            s0 += fast_tanh(wv[nf] + acc[mf8][nf][0]) * vv[nf];
            s1 += fast_tanh(wv[nf] + acc[mf8][nf][1]) * vv[nf];
            s2 += fast_tanh(wv[nf] + acc[mf8][nf][2]) * vv[nf];
            s3 += fast_tanh(wv[nf] + acc[mf8][nf][3]) * vv[nf];
        }
        #pragma unroll
        for (int off = 1; off < 16; off <<= 1) {
            s0 += __shfl_xor(s0, off, 16);
            s1 += __shfl_xor(s1, off, 16);
            s2 += __shfl_xor(s2, off, 16);
            s3 += __shfl_xor(s3, off, 16);
        }
        if (c == 0) {
            // interleaved A ownership: local row = wmb + mh*128 + mfl*16 + q*4
            int mh = mf8 >> 2, mfl = mf8 & 3;
            int row = wmb + mh * 128 + mfl * 16 + q * 4;
            e_red[(wid & 3) * 256 + row + 0] = s0;
            e_red[(wid & 3) * 256 + row + 1] = s1;
            e_red[(wid & 3) * 256 + row + 2] = s2;
            e_red[(wid & 3) * 256 + row + 3] = s3;
        }
    }
    __syncthreads();
    if (t < 256)
        e_part[(size_t)n_tile * M_TOT + m0 + t] =
            e_red[t] + e_red[256 + t] + e_red[512 + t] + e_red[768 + t];
}

// ---------------- fallback e-GEMM (ws too small): 128-tile on-the-fly cvt ----------------
__global__ __launch_bounds__(256) void k_gemm_fb(
        const float* __restrict__ enc, const __bf16* __restrict__ Ut,
        const float* __restrict__ w_part, const float* __restrict__ v,
        float* __restrict__ e_part) {
    __shared__ __bf16 lX[2][128 * 32];
    __shared__ __bf16 lU[2][128 * 32];
    __shared__ float  e_lds[2][128];

    const int t = threadIdx.x;
    const int bid = blockIdx.x;
    const int xcd = bid & 7;
    const int j_  = bid >> 3;
    const int m_tile = xcd * 64 + (j_ >> 3);
    const int n_tile = j_ & 7;
    const int m0 = m_tile * 128;
    const int n0 = n_tile * 128;
    const int wave = t >> 6;
    const int lane = t & 63;
    const int q = lane >> 4;
    const int c = lane & 15;
    const int wm = (wave >> 1) * 64;
    const int wn = (wave & 1) * 64;

    f32x4 acc[4][4];
    #pragma unroll
    for (int i = 0; i < 4; ++i)
        #pragma unroll
        for (int j = 0; j < 4; ++j)
            #pragma unroll
            for (int r = 0; r < 4; ++r) acc[i][j][r] = 0.f;

    const int lrow = lane >> 2;
    const int p    = lane & 3;
    const int sw   = (lrow >> 1) & 3;
    const int lcolS = ((p ^ sw)) * 8;
    const int xrow = wave * 32;

    const float*  gxa = enc + (size_t)(m0 + xrow + lrow) * 1024 + lcolS;
    const __bf16* gub = Ut  + (size_t)(n0 + xrow + lrow) * 1024 + lcolS;

    float4 f0, f1, f2, f3;
    auto loadA = [&](int kk) {
        const float* pp = gxa + kk;
        f0 = *(const float4*)pp;
        f1 = *(const float4*)(pp + 4);
        f2 = *(const float4*)(pp + 16 * 1024);
        f3 = *(const float4*)(pp + 16 * 1024 + 4);
    };
    auto writeA = [&](int bsel) {
        *(bf16x8*)(&lX[bsel][(xrow + lrow) * 32 + p * 8])      = pack8(f0, f1);
        *(bf16x8*)(&lX[bsel][(xrow + 16 + lrow) * 32 + p * 8]) = pack8(f2, f3);
    };
    auto stageB = [&](int kk, int bsel) {
        async_ld16(gub + kk,             &lU[bsel][xrow * 32]);
        async_ld16(gub + kk + 16 * 1024, &lU[bsel][(xrow + 16) * 32]);
    };
    const int fcol = (q ^ ((c >> 1) & 3)) * 8;
    auto compute = [&](int bsel) {
        bf16x8 af[4], bfr[4];
        #pragma unroll
        for (int i = 0; i < 4; ++i)
            af[i] = *(const bf16x8*)(&lX[bsel][(wm + i * 16 + c) * 32 + fcol]);
        #pragma unroll
        for (int j = 0; j < 4; ++j)
            bfr[j] = *(const bf16x8*)(&lU[bsel][(wn + j * 16 + c) * 32 + fcol]);
        #pragma unroll
        for (int i = 0; i < 4; ++i)
            #pragma unroll
            for (int j = 0; j < 4; ++j)
                acc[i][j] = __builtin_amdgcn_mfma_f32_16x16x32_bf16(af[i], bfr[j], acc[i][j], 0, 0, 0);
    };

    loadA(0);
    stageB(0, 0);
    writeA(0);
    __syncthreads();
    for (int kk = 0; kk < 1024; kk += 64) {
        if (kk + 32 < 1024) { loadA(kk + 32); stageB(kk + 32, 1); }
        compute(0);
        if (kk + 32 < 1024) writeA(1);
        __syncthreads();
        if (kk + 64 < 1024) { loadA(kk + 64); stageB(kk + 64, 0); }
        compute(1);
        if (kk + 64 < 1024) writeA(0);
        __syncthreads();
    }

    const int b_idx = m0 >> 11;
    float wv[4], vv[4];
    #pragma unroll
    for (int j = 0; j < 4; ++j) {
        int col = n0 + wn + j * 16 + c;
        float s = 0.f;
        #pragma unroll
        for (int pp = 0; pp < 8; ++pp) s += w_part[pp * 32768 + b_idx * 1024 + col];
        wv[j] = s;
        vv[j] = v[col];
    }
    #pragma unroll
    for (int i = 0; i < 4; ++i) {
        float s0 = 0.f, s1 = 0.f, s2 = 0.f, s3 = 0.f;
        #pragma unroll
        for (int j = 0; j < 4; ++j) {
            s0 += fast_tanh(wv[j] + acc[i][j][0]) * vv[j];
            s1 += fast_tanh(wv[j] + acc[i][j][1]) * vv[j];
            s2 += fast_tanh(wv[j] + acc[i][j][2]) * vv[j];
            s3 += fast_tanh(wv[j] + acc[i][j][3]) * vv[j];
        }
        #pragma unroll
        for (int off = 1; off < 16; off <<= 1) {
            s0 += __shfl_xor(s0, off, 16);
            s1 += __shfl_xor(s1, off, 16);
            s2 += __shfl_xor(s2, off, 16);
            s3 += __shfl_xor(s3, off, 16);
        }
        if (c == 0) {
            int row = wm + i * 16 + q * 4;
            e_lds[wave & 1][row + 0] = s0;
            e_lds[wave & 1][row + 1] = s1;
            e_lds[wave & 1][row + 2] = s2;
            e_lds[wave & 1][row + 3] = s3;
        }
    }
    __syncthreads();
    if (t < 128)
        e_part[(size_t)n_tile * M_TOT + m0 + t] = e_lds[0][t] + e_lds[1][t];
}

// ---------------- k4: softmax over S per batch (NP partial planes) ----------------
template<int NP>
__global__ __launch_bounds__(256) void k_softmax(const float* __restrict__ ep,
                                                 float* __restrict__ al) {
    int b = blockIdx.x, t = threadIdx.x;
    float ev[8];
    #pragma unroll
    for (int i = 0; i < 8; ++i) {
        int s = i * 256 + t;
        float x = 0.f;
        #pragma unroll
        for (int p = 0; p < NP; ++p) x += ep[p * M_TOT + b * 2048 + s];
        ev[i] = x;
    }
    float mx = ev[0];
    #pragma unroll
    for (int i = 1; i < 8; ++i) mx = fmaxf(mx, ev[i]);
    #pragma unroll
    for (int off = 1; off < 64; off <<= 1) mx = fmaxf(mx, __shfl_xor(mx, off, 64));
    __shared__ float redm[4];
    if ((t & 63) == 0) redm[t >> 6] = mx;
    __syncthreads();
    mx = fmaxf(fmaxf(redm[0], redm[1]), fmaxf(redm[2], redm[3]));

    float ex[8], sm = 0.f;
    #pragma unroll
    for (int i = 0; i < 8; ++i) { ex[i] = __expf(ev[i] - mx); sm += ex[i]; }
    #pragma unroll
    for (int off = 1; off < 64; off <<= 1) sm += __shfl_xor(sm, off, 64);
    __shared__ float reds[4];
    if ((t & 63) == 0) reds[t >> 6] = sm;
    __syncthreads();
    sm = reds[0] + reds[1] + reds[2] + reds[3];
    float inv = 1.f / sm;
    #pragma unroll
    for (int i = 0; i < 8; ++i) al[b * 2048 + i * 256 + t] = ex[i] * inv;
}

// ---------------- k5: context partials (fp32 enc) ----------------
__global__ __launch_bounds__(256) void k_ctx(const float* __restrict__ enc,
                                             const float* __restrict__ al,
                                             float* __restrict__ ctx_part) {
    int b  = blockIdx.x >> 5;
    int sc = blockIdx.x & 31;
    int t  = threadIdx.x;
    int e4 = t * 4;
    float ax = 0.f, ay = 0.f, az = 0.f, aw = 0.f;
    int sbase = sc * 64;
    for (int i = 0; i < 64; i += 4) {
        #pragma unroll
        for (int u = 0; u < 4; ++u) {
            int s = sbase + i + u;
            float a = al[b * 2048 + s];
            float4 x = *(const float4*)(enc + (size_t)(b * 2048 + s) * 1024 + e4);
            ax += a * x.x; ay += a * x.y; az += a * x.z; aw += a * x.w;
        }
    }
    float4 r; r.x = ax; r.y = ay; r.z = az; r.w = aw;
    *(float4*)(ctx_part + ((size_t)sc * 32 + b) * 1024 + e4) = r;
}

// ---------------- k6: final — ctx reduce + context out + FFN GEMV + tanh ----------------
__global__ __launch_bounds__(256) void k_final(const float* __restrict__ dec,
                                               const float* __restrict__ ffn,
                                               const float* __restrict__ ctx_part,
                                               float* __restrict__ out) {
    int b  = blockIdx.x >> 4;
    int dc = blockIdx.x & 15;
    int t  = threadIdx.x;
    __shared__ float cat[2048];
    __shared__ float red[4][64];

    #pragma unroll
    for (int r = 0; r < 4; ++r) {
        int e = r * 256 + t;
        cat[e] = dec[b * 1024 + e];
        float s = 0.f;
        #pragma unroll
        for (int p = 0; p < 32; ++p) s += ctx_part[((size_t)p * 32 + b) * 1024 + e];
        cat[1024 + e] = s;
        if (dc == 0) out[32768 + b * 1024 + e] = s;   // context output
    }
    __syncthreads();

    int dl = t & 63, ic = t >> 6;
    int d  = dc * 64 + dl;
    float acc = 0.f;
    int i0 = ic * 512;
    for (int i = 0; i < 512; i += 4) {
        float4 cv = *(const float4*)(cat + i0 + i);
        const float* fr = ffn + (size_t)(i0 + i) * 1024 + d;
        acc += cv.x * fr[0];
        acc += cv.y * fr[1024];
        acc += cv.z * fr[2048];
        acc += cv.w * fr[3072];
    }
    red[ic][dl] = acc;
    __syncthreads();
    if (t < 64) {
        float s = red[0][t] + red[1][t] + red[2][t] + red[3][t];
        out[b * 1024 + dc * 64 + t] = fast_tanh(s);
    }
}

// ---------------- launch ----------------
extern "C" void kernel_launch(void* const* d_in, const int* in_sizes, int n_in,
                              void* d_out, int out_size, void* d_ws, size_t ws_size,
                              hipStream_t stream) {
    const float* enc = (const float*)d_in[0];
    const float* dec = (const float*)d_in[1];
    const float* Ua  = (const float*)d_in[2];
    const float* Wa  = (const float*)d_in[3];
    const float* vt  = (const float*)d_in[4];
    const float* ffn = (const float*)d_in[5];
    float* out = (float*)d_out;

    char* ws = (char*)d_ws;
    size_t off = 0;
    __bf16* Ut       = (__bf16*)(ws + off); off += (size_t)A_ * E_ * 2;            // 2 MiB
    float*  e_part   = (float*)(ws + off);  off += (size_t)8 * M_TOT * 4;          // 2 MiB
    float*  al       = (float*)(ws + off);  off += (size_t)M_TOT * 4;              // 256 KiB
    float*  w_part   = (float*)(ws + off);  off += (size_t)8 * B_ * 1024 * 4;      // 1 MiB
    float*  ctx_part = (float*)(ws + off);  off += (size_t)32 * B_ * 1024 * 4;     // 4 MiB
    __bf16* encB     = (__bf16*)(ws + off); off += (size_t)M_TOT * E_ * 2;         // 128 MiB
    const bool use_async = ws_size >= off;

    if (use_async) {
        k_prep<<<9472, 256, 0, stream>>>(enc, encB, Ua, Ut, dec, Wa, w_part);
        k_gemm8<<<1024, 512, 0, stream>>>(encB, Ut, w_part, vt, e_part);
        k_softmax<4><<<B_, 256, 0, stream>>>(e_part, al);
    } else {
        k_prep<<<9472, 256, 0, stream>>>(enc, encB, Ua, Ut, dec, Wa, w_part);
        k_gemm_fb<<<4096, 256, 0, stream>>>(enc, Ut, w_part, vt, e_part);
        k_softmax<8><<<B_, 256, 0, stream>>>(e_part, al);
    }
    k_ctx<<<B_ * 32, 256, 0, stream>>>(enc, al, ctx_part);
    k_final<<<B_ * 16, 256, 0, stream>>>(dec, ffn, ctx_part, out);
}